// Round 3
// baseline (91.479 us; speedup 1.0000x reference)
//
#include <hip/hip_runtime.h>

typedef __attribute__((ext_vector_type(4))) float f32x4;
typedef __attribute__((ext_vector_type(8))) short short8;
typedef __attribute__((ext_vector_type(8))) __bf16 bf16x8;

constexpr int kN = 4096;
constexpr int kF = 256;
constexpr int kH = 4;
constexpr int kD = 64;
constexpr float kLog2e = 1.4426950408889634f;

__device__ __forceinline__ unsigned short f2us(float x) {
  __bf16 b = (__bf16)x;
  return __builtin_bit_cast(unsigned short, b);
}

// ---------------------------------------------------------------------------
// k_wswz: W (fp32, HxFxD) -> bf16 MFMA B-fragments for k_wh.
// Frag element (lane,e) of (h,ks,dt): W[h][ks*32 + 8*(lane>>4) + e][dt*16 + (lane&15)]
// stored at wfrag[(h*2048 + (ks*4+dt)*64 + lane)*8 + e].
// ---------------------------------------------------------------------------
__global__ __launch_bounds__(256) void k_wswz(const float* __restrict__ W,
                                              unsigned short* __restrict__ wfrag) {
  const int h = blockIdx.x;
  const int t = threadIdx.x;
#pragma unroll
  for (int j = 0; j < 8; j++) {
    const int lf = t + j * 256;  // 0..2047
    const int lane = lf & 63;
    const int dt = (lf >> 6) & 3;
    const int ks = lf >> 8;
    const int d = dt * 16 + (lane & 15);
    const int i0 = ks * 32 + 8 * (lane >> 4);
    unsigned short v[8];
#pragma unroll
    for (int e = 0; e < 8; e++)
      v[e] = f2us(W[((size_t)h * kF + i0 + e) * kD + d]);
    *reinterpret_cast<short8*>(wfrag + ((size_t)(h * 2048 + lf) << 3)) =
        *reinterpret_cast<const short8*>(v);
  }
}

// ---------------------------------------------------------------------------
// k_wh: Wh = h @ W[h] via MFMA (B-frags linear from wfrag); writes whb
// (bf16, pre-swizzled B-frag order for k_attn) AND s_src/s_dst (dot of the
// fp32 acc with a_src/a_dst) AND atomicMax'ed biased-uint key of max s_dst.
// ---------------------------------------------------------------------------
__global__ __launch_bounds__(256) void k_wh(const float* __restrict__ hmat,
                                            const unsigned short* __restrict__ wfrag,
                                            const float* __restrict__ a_src,
                                            const float* __restrict__ a_dst,
                                            unsigned short* __restrict__ whb,
                                            float* __restrict__ s_src,
                                            float* __restrict__ s_dst,
                                            unsigned int* __restrict__ MhKey) {
  const int h = blockIdx.x & 3, rb = blockIdx.x >> 2;
  const int row0 = rb * 64;
  const int t = threadIdx.x;
  const int wave = t >> 6, lane = t & 63;
  const int lr = lane & 15, lg = lane >> 4;
  const int nrow = row0 + wave * 16 + lr;
  f32x4 acc[4] = {};
  const float* hrow = hmat + (size_t)nrow * kF + 8 * lg;
  const short8* wf = reinterpret_cast<const short8*>(wfrag) + h * 2048 + lane;
#pragma unroll
  for (int ks = 0; ks < 8; ks++) {
    const f32x4 h0 = *reinterpret_cast<const f32x4*>(hrow + ks * 32);
    const f32x4 h1 = *reinterpret_cast<const f32x4*>(hrow + ks * 32 + 4);
    bf16x8 af;
#pragma unroll
    for (int j = 0; j < 4; j++) { af[j] = (__bf16)h0[j]; af[4 + j] = (__bf16)h1[j]; }
#pragma unroll
    for (int dt = 0; dt < 4; dt++) {
      const short8 bs = wf[(ks * 4 + dt) * 64];
      acc[dt] = __builtin_amdgcn_mfma_f32_16x16x32_bf16(af, __builtin_bit_cast(bf16x8, bs), acc[dt], 0, 0, 0);
    }
  }
  // whb scatter: C elem (row n = row0+wave*16+lg*4+r, col d = dt*16+lr)
#pragma unroll
  for (int dt = 0; dt < 4; dt++) {
#pragma unroll
    for (int r = 0; r < 4; r++) {
      const int n = row0 + wave * 16 + lg * 4 + r;
      const int mstep = n >> 5, kl = n & 31;
      const int lane2 = ((kl >> 3) << 4) | lr;
      const int e = kl & 7;
      whb[((((size_t)(h * 128 + mstep) * 4 + dt) * 64 + lane2) << 3) + e] = f2us(acc[dt][r]);
    }
  }
  // s epilogue: s[n] = sum_d Wh[n][d] * a[d]
  float as4[4], ad4[4];
#pragma unroll
  for (int dt = 0; dt < 4; dt++) {
    as4[dt] = a_src[h * kD + dt * 16 + lr];
    ad4[dt] = a_dst[h * kD + dt * 16 + lr];
  }
  float wmax = -1e30f;
#pragma unroll
  for (int r = 0; r < 4; r++) {
    float ps = acc[0][r] * as4[0] + acc[1][r] * as4[1] + acc[2][r] * as4[2] + acc[3][r] * as4[3];
    float pd = acc[0][r] * ad4[0] + acc[1][r] * ad4[1] + acc[2][r] * ad4[2] + acc[3][r] * ad4[3];
#pragma unroll
    for (int off = 1; off < 16; off <<= 1) {
      ps += __shfl_xor(ps, off);
      pd += __shfl_xor(pd, off);
    }
    const int n = row0 + wave * 16 + lg * 4 + r;
    if (lr == 0) { s_src[h * kN + n] = ps; s_dst[h * kN + n] = pd; }
    wmax = fmaxf(wmax, pd);  // butterfly gave full sum on all lanes
  }
  wmax = fmaxf(wmax, __shfl_xor(wmax, 16));
  wmax = fmaxf(wmax, __shfl_xor(wmax, 32));
  if (lane == 0) {
    const unsigned int key = (unsigned int)fmaxf(0.0f, (wmax + 512.0f) * 4096.0f) + 1u;
    atomicMax(&MhKey[h], key);
  }
}

// ---------------------------------------------------------------------------
// k_abits: adj (fp32 0/1) -> bitmask via __ballot; every load instruction is
// 256 B contiguous (lane l reads element base + 64c + l).
// ---------------------------------------------------------------------------
__global__ __launch_bounds__(256) void k_abits(const float* __restrict__ adj,
                                               unsigned int* __restrict__ bits) {
  const int gw = (blockIdx.x * 256 + threadIdx.x) >> 6;  // wave id, 16384 total
  const int lane = threadIdx.x & 63;
  const size_t ebase = (size_t)gw * 1024;
  const float* p = adj + ebase + lane;
  unsigned int myword = 0;
#pragma unroll
  for (int c = 0; c < 16; c++) {
    const unsigned long long b = __ballot(p[c * 64] != 0.0f);
    const unsigned int sel = (lane & 1) ? (unsigned int)(b >> 32) : (unsigned int)b;
    if ((lane >> 1) == c) myword = sel;
  }
  if (lane < 32) bits[(ebase >> 5) + lane] = myword;
}

// p = mask * max(E1*K1, E2*K2)   (exp2 fully hoisted out of the inner loop)
__device__ __forceinline__ bf16x8 make_p2(const f32x4 E1a, const f32x4 E1b,
                                          const f32x4 E2a, const f32x4 E2b,
                                          const float K1, const float K2,
                                          const unsigned int m) {
  bf16x8 r;
#pragma unroll
  for (int j = 0; j < 4; j++) {
    const float pv = fmaxf(E1a[j] * K1, E2a[j] * K2);
    r[j] = (__bf16)((m & (1u << j)) ? pv : 0.0f);
  }
#pragma unroll
  for (int j = 0; j < 4; j++) {
    const float pv = fmaxf(E1b[j] * K1, E2b[j] * K2);
    r[4 + j] = (__bf16)((m & (16u << j)) ? pv : 0.0f);
  }
  return r;
}

// ---------------------------------------------------------------------------
// k_attn: 512 blocks = 128 rowgroups x 4 colsplits (2 blocks/CU), 8 waves =
// 4 heads x 2 col-interleaves, BQ=32, 16 iters of 64 cols. Per-column
// E1=e^{sd}, E2=e^{0.2 sd} staged in LDS; per-row K1,K2 in registers; inner
// loop is mul/mul/max/select only. Partials atomicAdd'ed into accC/zC.
// ---------------------------------------------------------------------------
__global__ __launch_bounds__(512, 4) void k_attn(const unsigned char* __restrict__ bitsb,
                                                 const unsigned short* __restrict__ whb,
                                                 const float* __restrict__ s_src,
                                                 const float* __restrict__ s_dst,
                                                 const unsigned int* __restrict__ MhKey,
                                                 float* __restrict__ accC,
                                                 float* __restrict__ zC) {
  const int bid = blockIdx.x;
  const int rb = bid >> 2, cs = bid & 3;
  const int row0 = rb * 32;
  const int colbase = cs * 1024;
  const int t = threadIdx.x;
  const int wave = t >> 6, lane = t & 63;
  const int h = wave & 3, q = wave >> 2;
  const int lr = lane & 15, lg = lane >> 4;

  __shared__ float el1[4][1024];
  __shared__ float el2[4][1024];

#pragma unroll
  for (int j = 0; j < 2; j++) {
    const int idx = t + j * 512;  // 0..1023
    const int hh = idx >> 8, c4 = (idx & 255) * 4;
    const f32x4 sd = *reinterpret_cast<const f32x4*>(s_dst + hh * kN + colbase + c4);
    f32x4 e1, e2;
#pragma unroll
    for (int i = 0; i < 4; i++) {
      const float u = sd[i] * kLog2e;
      e1[i] = __builtin_amdgcn_exp2f(u);
      e2[i] = __builtin_amdgcn_exp2f(0.2f * u);
    }
    *reinterpret_cast<f32x4*>(&el1[hh][c4]) = e1;
    *reinterpret_cast<f32x4*>(&el2[hh][c4]) = e2;
  }
  __syncthreads();

  const float M = (float)MhKey[h] * (1.0f / 4096.0f) - 512.0f;  // upper bound of max sd
  float K1[2], K2[2];
#pragma unroll
  for (int rt = 0; rt < 2; rt++) {
    const float A = s_src[h * kN + row0 + rt * 16 + lr];
    const float x = A + M;
    const float B = fmaxf(x, 0.2f * x);
    K1[rt] = __builtin_amdgcn_exp2f((A - B) * kLog2e);
    K2[rt] = __builtin_amdgcn_exp2f((0.2f * A - B) * kLog2e);
  }

  f32x4 acc[2][4] = {};
  f32x4 accz[2] = {};
  bf16x8 ones;
#pragma unroll
  for (int e = 0; e < 8; e++) ones[e] = (__bf16)1.0f;

  const size_t mB0 = (size_t)(row0 + lr) * 512 + ((colbase + q * 32) >> 3) + lg;
  const size_t mB1 = mB0 + (size_t)16 * 512;
  const float* e1p = &el1[h][q * 32 + 8 * lg];
  const float* e2p = &el2[h][q * 32 + 8 * lg];
  const short8* wb = reinterpret_cast<const short8*>(whb) + (size_t)h * 32768 + lane;
  const int mstep0 = cs * 32 + q;

  // 2-deep mask prefetch, 1-deep B-frag prefetch
  unsigned int ma0 = bitsb[mB0], ma1 = bitsb[mB1];
  unsigned int mb0 = bitsb[mB0 + 8], mb1 = bitsb[mB1 + 8];
  short8 bw0, bw1, bw2, bw3;
  {
    const short8* p = wb + (size_t)mstep0 * 256;
    bw0 = p[0]; bw1 = p[64]; bw2 = p[128]; bw3 = p[192];
  }

  for (int it = 0; it < 16; it++) {
    const unsigned int cm0 = ma0, cm1 = ma1;
    ma0 = mb0; ma1 = mb1;
    if (it + 2 < 16) { mb0 = bitsb[mB0 + (it + 2) * 8]; mb1 = bitsb[mB1 + (it + 2) * 8]; }

    const short8 cb0 = bw0, cb1 = bw1, cb2 = bw2, cb3 = bw3;
    if (it + 1 < 16) {
      const short8* p = wb + (size_t)(mstep0 + (it + 1) * 2) * 256;
      bw0 = p[0]; bw1 = p[64]; bw2 = p[128]; bw3 = p[192];
    }

    const f32x4 E1a = *reinterpret_cast<const f32x4*>(e1p + it * 64);
    const f32x4 E1b = *reinterpret_cast<const f32x4*>(e1p + it * 64 + 4);
    const f32x4 E2a = *reinterpret_cast<const f32x4*>(e2p + it * 64);
    const f32x4 E2b = *reinterpret_cast<const f32x4*>(e2p + it * 64 + 4);

    const bf16x8 P0 = make_p2(E1a, E1b, E2a, E2b, K1[0], K2[0], cm0);
    const bf16x8 P1 = make_p2(E1a, E1b, E2a, E2b, K1[1], K2[1], cm1);
    const bf16x8 B0 = __builtin_bit_cast(bf16x8, cb0);
    const bf16x8 B1 = __builtin_bit_cast(bf16x8, cb1);
    const bf16x8 B2 = __builtin_bit_cast(bf16x8, cb2);
    const bf16x8 B3 = __builtin_bit_cast(bf16x8, cb3);

    acc[0][0] = __builtin_amdgcn_mfma_f32_16x16x32_bf16(P0, B0, acc[0][0], 0, 0, 0);
    acc[0][1] = __builtin_amdgcn_mfma_f32_16x16x32_bf16(P0, B1, acc[0][1], 0, 0, 0);
    acc[0][2] = __builtin_amdgcn_mfma_f32_16x16x32_bf16(P0, B2, acc[0][2], 0, 0, 0);
    acc[0][3] = __builtin_amdgcn_mfma_f32_16x16x32_bf16(P0, B3, acc[0][3], 0, 0, 0);
    accz[0]   = __builtin_amdgcn_mfma_f32_16x16x32_bf16(P0, ones, accz[0], 0, 0, 0);
    acc[1][0] = __builtin_amdgcn_mfma_f32_16x16x32_bf16(P1, B0, acc[1][0], 0, 0, 0);
    acc[1][1] = __builtin_amdgcn_mfma_f32_16x16x32_bf16(P1, B1, acc[1][1], 0, 0, 0);
    acc[1][2] = __builtin_amdgcn_mfma_f32_16x16x32_bf16(P1, B2, acc[1][2], 0, 0, 0);
    acc[1][3] = __builtin_amdgcn_mfma_f32_16x16x32_bf16(P1, B3, acc[1][3], 0, 0, 0);
    accz[1]   = __builtin_amdgcn_mfma_f32_16x16x32_bf16(P1, ones, accz[1], 0, 0, 0);
  }

  // epilogue: atomic combine (4 writers per address: cs = 0..3)
#pragma unroll
  for (int rt = 0; rt < 2; rt++) {
#pragma unroll
    for (int dt = 0; dt < 4; dt++)
#pragma unroll
      for (int r = 0; r < 4; r++) {
        const int n = row0 + rt * 16 + lg * 4 + r;
        const int d = dt * 16 + lr;
        atomicAdd(&accC[((size_t)h * kN + n) * kD + d], acc[rt][dt][r]);
      }
    if (lr == 0) {
#pragma unroll
      for (int r = 0; r < 4; r++)
        atomicAdd(&zC[(size_t)h * kN + row0 + rt * 16 + lg * 4 + r], accz[rt][r]);
    }
  }
}

// ---------------------------------------------------------------------------
// k_fin: out[n][h*64+d] = elu( accC / zC )
// ---------------------------------------------------------------------------
__global__ __launch_bounds__(256) void k_fin(const float* __restrict__ accC,
                                             const float* __restrict__ zC,
                                             float* __restrict__ out) {
  const int idx = blockIdx.x * 256 + threadIdx.x;  // 262144 float4s
  const int d4 = idx & 15;
  const int hh = (idx >> 4) & 3;
  const int n = idx >> 6;
  const f32x4 v = reinterpret_cast<const f32x4*>(accC)[((size_t)hh * kN + n) * 16 + d4];
  const float z = zC[hh * kN + n];
  const float rz = 1.0f / z;
  f32x4 o;
#pragma unroll
  for (int j = 0; j < 4; j++) {
    const float x = v[j] * rz;
    o[j] = x > 0.0f ? x : (__builtin_amdgcn_exp2f(x * kLog2e) - 1.0f);
  }
  reinterpret_cast<f32x4*>(out)[(size_t)n * 64 + hh * 16 + d4] = o;
}

extern "C" void kernel_launch(void* const* d_in, const int* in_sizes, int n_in,
                              void* d_out, int out_size, void* d_ws, size_t ws_size,
                              hipStream_t stream) {
  const float* hmat  = (const float*)d_in[0];
  const float* adj   = (const float*)d_in[1];
  const float* W     = (const float*)d_in[2];
  const float* a_src = (const float*)d_in[3];
  const float* a_dst = (const float*)d_in[4];
  float* out = (float*)d_out;

  char* ws = (char*)d_ws;
  unsigned short* whb   = (unsigned short*)(ws);             // 2 MB   @0
  unsigned short* wfrag = (unsigned short*)(ws + 0x200000);  // 128 KB
  float* s_src  = (float*)(ws + 0x220000);                   // 64 KB
  float* s_dst  = (float*)(ws + 0x230000);                   // 64 KB
  unsigned int* bits = (unsigned int*)(ws + 0x240000);       // 2 MB
  float* accC   = (float*)(ws + 0x440000);                   // 4 MB
  float* zC     = (float*)(ws + 0x840000);                   // 64 KB
  unsigned int* MhKey = (unsigned int*)(ws + 0x850000);      // 16 B

  hipMemsetAsync(ws + 0x440000, 0, 0x410010, stream);  // accC + zC + MhKey
  hipLaunchKernelGGL(k_wswz, dim3(4), dim3(256), 0, stream, W, wfrag);
  hipLaunchKernelGGL(k_wh, dim3(256), dim3(256), 0, stream,
                     hmat, wfrag, a_src, a_dst, whb, s_src, s_dst, MhKey);
  hipLaunchKernelGGL(k_abits, dim3(4096), dim3(256), 0, stream, adj, bits);
  hipLaunchKernelGGL(k_attn, dim3(512), dim3(512), 0, stream,
                     (const unsigned char*)bits, whb, s_src, s_dst, MhKey, accC, zC);
  hipLaunchKernelGGL(k_fin, dim3(1024), dim3(256), 0, stream, accC, zC, out);
}

// Round 5
// 77.970 us; speedup vs baseline: 1.1733x; 1.1733x over previous
//
#include <hip/hip_runtime.h>

typedef __attribute__((ext_vector_type(4))) float f32x4;
typedef __attribute__((ext_vector_type(8))) short short8;
typedef __attribute__((ext_vector_type(8))) __bf16 bf16x8;

constexpr int kN = 4096;
constexpr int kF = 256;
constexpr int kH = 4;
constexpr int kD = 64;
constexpr float kLog2e = 1.4426950408889634f;

__device__ __forceinline__ unsigned short f2us(float x) {
  __bf16 b = (__bf16)x;
  return __builtin_bit_cast(unsigned short, b);
}

// ---------------------------------------------------------------------------
// k_wswz: W (fp32, HxFxD) -> bf16 MFMA B-fragments for k_wh.
// ---------------------------------------------------------------------------
__global__ __launch_bounds__(256) void k_wswz(const float* __restrict__ W,
                                              unsigned short* __restrict__ wfrag) {
  const int h = blockIdx.x;
  const int t = threadIdx.x;
#pragma unroll
  for (int j = 0; j < 8; j++) {
    const int lf = t + j * 256;  // 0..2047
    const int lane = lf & 63;
    const int dt = (lf >> 6) & 3;
    const int ks = lf >> 8;
    const int d = dt * 16 + (lane & 15);
    const int i0 = ks * 32 + 8 * (lane >> 4);
    unsigned short v[8];
#pragma unroll
    for (int e = 0; e < 8; e++)
      v[e] = f2us(W[((size_t)h * kF + i0 + e) * kD + d]);
    *reinterpret_cast<short8*>(wfrag + ((size_t)(h * 2048 + lf) << 3)) =
        *reinterpret_cast<const short8*>(v);
  }
}

// ---------------------------------------------------------------------------
// k_wh: Wh = h @ W[h] via MFMA; writes whb (bf16, pre-swizzled B-frag order)
// + s_src/s_dst (fp32 acc dotted with a vectors) + atomicMax'ed max-key.
// ---------------------------------------------------------------------------
__global__ __launch_bounds__(256) void k_wh(const float* __restrict__ hmat,
                                            const unsigned short* __restrict__ wfrag,
                                            const float* __restrict__ a_src,
                                            const float* __restrict__ a_dst,
                                            unsigned short* __restrict__ whb,
                                            float* __restrict__ s_src,
                                            float* __restrict__ s_dst,
                                            unsigned int* __restrict__ MhKey) {
  const int h = blockIdx.x & 3, rb = blockIdx.x >> 2;
  const int row0 = rb * 64;
  const int t = threadIdx.x;
  const int wave = t >> 6, lane = t & 63;
  const int lr = lane & 15, lg = lane >> 4;
  const int nrow = row0 + wave * 16 + lr;
  f32x4 acc[4] = {};
  const float* hrow = hmat + (size_t)nrow * kF + 8 * lg;
  const short8* wf = reinterpret_cast<const short8*>(wfrag) + h * 2048 + lane;
#pragma unroll
  for (int ks = 0; ks < 8; ks++) {
    const f32x4 h0 = *reinterpret_cast<const f32x4*>(hrow + ks * 32);
    const f32x4 h1 = *reinterpret_cast<const f32x4*>(hrow + ks * 32 + 4);
    bf16x8 af;
#pragma unroll
    for (int j = 0; j < 4; j++) { af[j] = (__bf16)h0[j]; af[4 + j] = (__bf16)h1[j]; }
#pragma unroll
    for (int dt = 0; dt < 4; dt++) {
      const short8 bs = wf[(ks * 4 + dt) * 64];
      acc[dt] = __builtin_amdgcn_mfma_f32_16x16x32_bf16(af, __builtin_bit_cast(bf16x8, bs), acc[dt], 0, 0, 0);
    }
  }
#pragma unroll
  for (int dt = 0; dt < 4; dt++) {
#pragma unroll
    for (int r = 0; r < 4; r++) {
      const int n = row0 + wave * 16 + lg * 4 + r;
      const int mstep = n >> 5, kl = n & 31;
      const int lane2 = ((kl >> 3) << 4) | lr;
      const int e = kl & 7;
      whb[((((size_t)(h * 128 + mstep) * 4 + dt) * 64 + lane2) << 3) + e] = f2us(acc[dt][r]);
    }
  }
  float as4[4], ad4[4];
#pragma unroll
  for (int dt = 0; dt < 4; dt++) {
    as4[dt] = a_src[h * kD + dt * 16 + lr];
    ad4[dt] = a_dst[h * kD + dt * 16 + lr];
  }
  float wmax = -1e30f;
#pragma unroll
  for (int r = 0; r < 4; r++) {
    float ps = acc[0][r] * as4[0] + acc[1][r] * as4[1] + acc[2][r] * as4[2] + acc[3][r] * as4[3];
    float pd = acc[0][r] * ad4[0] + acc[1][r] * ad4[1] + acc[2][r] * ad4[2] + acc[3][r] * ad4[3];
#pragma unroll
    for (int off = 1; off < 16; off <<= 1) {
      ps += __shfl_xor(ps, off);
      pd += __shfl_xor(pd, off);
    }
    const int n = row0 + wave * 16 + lg * 4 + r;
    if (lr == 0) { s_src[h * kN + n] = ps; s_dst[h * kN + n] = pd; }
    wmax = fmaxf(wmax, pd);
  }
  wmax = fmaxf(wmax, __shfl_xor(wmax, 16));
  wmax = fmaxf(wmax, __shfl_xor(wmax, 32));
  if (lane == 0) {
    const unsigned int key = (unsigned int)fmaxf(0.0f, (wmax + 512.0f) * 4096.0f) + 1u;
    atomicMax(&MhKey[h], key);
  }
}

// ---------------------------------------------------------------------------
// k_abits: adj (fp32 0/1) -> bitmask via __ballot (coalesced 256B loads).
// ---------------------------------------------------------------------------
__global__ __launch_bounds__(256) void k_abits(const float* __restrict__ adj,
                                               unsigned int* __restrict__ bits) {
  const int gw = (blockIdx.x * 256 + threadIdx.x) >> 6;  // wave id, 16384 total
  const int lane = threadIdx.x & 63;
  const size_t ebase = (size_t)gw * 1024;
  const float* p = adj + ebase + lane;
  unsigned int myword = 0;
#pragma unroll
  for (int c = 0; c < 16; c++) {
    const unsigned long long b = __ballot(p[c * 64] != 0.0f);
    const unsigned int sel = (lane & 1) ? (unsigned int)(b >> 32) : (unsigned int)b;
    if ((lane >> 1) == c) myword = sel;
  }
  if (lane < 32) bits[(ebase >> 5) + lane] = myword;
}

// p = mask * max(E1*K1, E2*K2)
__device__ __forceinline__ bf16x8 make_p2(const f32x4 E1a, const f32x4 E1b,
                                          const f32x4 E2a, const f32x4 E2b,
                                          const float K1, const float K2,
                                          const unsigned int m) {
  bf16x8 r;
#pragma unroll
  for (int j = 0; j < 4; j++) {
    const float pv = fmaxf(E1a[j] * K1, E2a[j] * K2);
    r[j] = (__bf16)((m & (1u << j)) ? pv : 0.0f);
  }
#pragma unroll
  for (int j = 0; j < 4; j++) {
    const float pv = fmaxf(E1b[j] * K1, E2b[j] * K2);
    r[4 + j] = (__bf16)((m & (16u << j)) ? pv : 0.0f);
  }
  return r;
}

// ---------------------------------------------------------------------------
// k_attn: 512 blocks = 256 rowgroups(16 rows) x 2 col-halves(2048).
// 8 waves = 4 heads x 2 col-interleaves (q). q=0/q=1 partials are combined
// via an LDS exchange (NOT global atomics); then each (cs,h,n,d) partial is
// written exactly once to accP; k_fin combines the 2 col-splits.
// LDS: per-column E1=e^{sd}, E2=e^{0.2 sd} (64 KB -> 2 blocks/CU).
// ---------------------------------------------------------------------------
__global__ __launch_bounds__(512, 4) void k_attn(const unsigned char* __restrict__ bitsb,
                                                 const unsigned short* __restrict__ whb,
                                                 const float* __restrict__ s_src,
                                                 const float* __restrict__ s_dst,
                                                 const unsigned int* __restrict__ MhKey,
                                                 float* __restrict__ accP,
                                                 float* __restrict__ zP) {
  const int bid = blockIdx.x;
  const int rb = bid >> 1, cs = bid & 1;
  const int row0 = rb * 16;
  const int colbase = cs * 2048;
  const int t = threadIdx.x;
  const int wave = t >> 6, lane = t & 63;
  const int h = wave & 3, q = wave >> 2;
  const int lr = lane & 15, lg = lane >> 4;

  __shared__ float el1[4][2048];
  __shared__ float el2[4][2048];
  __shared__ float zx[4][16];

#pragma unroll
  for (int j = 0; j < 4; j++) {
    const int idx = t + j * 512;  // 0..2047 f32x4 slots
    const int hh = idx >> 9, c4 = (idx & 511) * 4;
    const f32x4 sd = *reinterpret_cast<const f32x4*>(s_dst + hh * kN + colbase + c4);
    f32x4 e1, e2;
#pragma unroll
    for (int i = 0; i < 4; i++) {
      const float u = sd[i] * kLog2e;
      e1[i] = __builtin_amdgcn_exp2f(u);
      e2[i] = __builtin_amdgcn_exp2f(0.2f * u);
    }
    *reinterpret_cast<f32x4*>(&el1[hh][c4]) = e1;
    *reinterpret_cast<f32x4*>(&el2[hh][c4]) = e2;
  }
  __syncthreads();

  const float M = (float)MhKey[h] * (1.0f / 4096.0f) - 512.0f;
  const float A = s_src[h * kN + row0 + lr];
  const float xb = A + M;
  const float B = fmaxf(xb, 0.2f * xb);
  const float K1 = __builtin_amdgcn_exp2f((A - B) * kLog2e);
  const float K2 = __builtin_amdgcn_exp2f((0.2f * A - B) * kLog2e);

  f32x4 acc[4] = {};
  f32x4 accz = {};
  bf16x8 ones;
#pragma unroll
  for (int e = 0; e < 8; e++) ones[e] = (__bf16)1.0f;

  const size_t mB = (size_t)(row0 + lr) * 512 + (colbase >> 3) + q * 4 + lg;
  const float* e1p = &el1[h][q * 32 + 8 * lg];
  const float* e2p = &el2[h][q * 32 + 8 * lg];
  const short8* wb = reinterpret_cast<const short8*>(whb) + (size_t)h * 32768 + lane;
  const int mstep0 = cs * 64 + q;

  // 2-deep mask prefetch, 1-deep B-frag prefetch
  unsigned int ma = bitsb[mB];
  unsigned int mb = bitsb[mB + 8];
  short8 bw0, bw1, bw2, bw3;
  {
    const short8* p = wb + (size_t)mstep0 * 256;
    bw0 = p[0]; bw1 = p[64]; bw2 = p[128]; bw3 = p[192];
  }

  for (int it = 0; it < 32; it++) {
    const unsigned int cm = ma;
    ma = mb;
    if (it + 2 < 32) mb = bitsb[mB + (it + 2) * 8];

    const short8 cb0 = bw0, cb1 = bw1, cb2 = bw2, cb3 = bw3;
    if (it + 1 < 32) {
      const short8* p = wb + (size_t)(mstep0 + (it + 1) * 2) * 256;
      bw0 = p[0]; bw1 = p[64]; bw2 = p[128]; bw3 = p[192];
    }

    const f32x4 E1a = *reinterpret_cast<const f32x4*>(e1p + it * 64);
    const f32x4 E1b = *reinterpret_cast<const f32x4*>(e1p + it * 64 + 4);
    const f32x4 E2a = *reinterpret_cast<const f32x4*>(e2p + it * 64);
    const f32x4 E2b = *reinterpret_cast<const f32x4*>(e2p + it * 64 + 4);

    const bf16x8 P0 = make_p2(E1a, E1b, E2a, E2b, K1, K2, cm);
    const bf16x8 B0 = __builtin_bit_cast(bf16x8, cb0);
    const bf16x8 B1 = __builtin_bit_cast(bf16x8, cb1);
    const bf16x8 B2 = __builtin_bit_cast(bf16x8, cb2);
    const bf16x8 B3 = __builtin_bit_cast(bf16x8, cb3);

    acc[0] = __builtin_amdgcn_mfma_f32_16x16x32_bf16(P0, B0, acc[0], 0, 0, 0);
    acc[1] = __builtin_amdgcn_mfma_f32_16x16x32_bf16(P0, B1, acc[1], 0, 0, 0);
    acc[2] = __builtin_amdgcn_mfma_f32_16x16x32_bf16(P0, B2, acc[2], 0, 0, 0);
    acc[3] = __builtin_amdgcn_mfma_f32_16x16x32_bf16(P0, B3, acc[3], 0, 0, 0);
    accz   = __builtin_amdgcn_mfma_f32_16x16x32_bf16(P0, ones, accz, 0, 0, 0);
  }

  // ---- q-combine via LDS (el1 is dead now), then single plain store ----
  __syncthreads();
  if (q == 1) {
    float* dst = &el1[h][0];
#pragma unroll
    for (int dt = 0; dt < 4; dt++)
      *reinterpret_cast<f32x4*>(dst + (dt * 64 + lane) * 4) = acc[dt];
    if (lr == 0) {
#pragma unroll
      for (int r = 0; r < 4; r++) zx[h][lg * 4 + r] = accz[r];
    }
  }
  __syncthreads();
  if (q == 0) {
    const float* src = &el1[h][0];
#pragma unroll
    for (int dt = 0; dt < 4; dt++)
      acc[dt] += *reinterpret_cast<const f32x4*>(src + (dt * 64 + lane) * 4);

    const size_t ob = ((size_t)(cs * 4 + h) * kN + row0) * kD;
#pragma unroll
    for (int dt = 0; dt < 4; dt++)
#pragma unroll
      for (int r = 0; r < 4; r++)
        accP[ob + (size_t)(lg * 4 + r) * kD + dt * 16 + lr] = acc[dt][r];
    if (lr == 0) {
#pragma unroll
      for (int r = 0; r < 4; r++)
        zP[(size_t)(cs * 4 + h) * kN + row0 + lg * 4 + r] = accz[r] + zx[h][lg * 4 + r];
    }
  }
}

// ---------------------------------------------------------------------------
// k_fin: out[n][h*64+d] = elu( (acc0+acc1) / (z0+z1) )
// ---------------------------------------------------------------------------
__global__ __launch_bounds__(256) void k_fin(const float* __restrict__ accP,
                                             const float* __restrict__ zP,
                                             float* __restrict__ out) {
  const int idx = blockIdx.x * 256 + threadIdx.x;  // 262144 float4s
  const int d4 = idx & 15;
  const int hh = (idx >> 4) & 3;
  const int n = idx >> 6;
  const f32x4 v0 = reinterpret_cast<const f32x4*>(accP)[((size_t)hh * kN + n) * 16 + d4];
  const f32x4 v1 = reinterpret_cast<const f32x4*>(accP)[((size_t)(4 + hh) * kN + n) * 16 + d4];
  const f32x4 v = v0 + v1;
  const float z = zP[(size_t)hh * kN + n] + zP[(size_t)(4 + hh) * kN + n];
  const float rz = 1.0f / z;
  f32x4 o;
#pragma unroll
  for (int j = 0; j < 4; j++) {
    const float x = v[j] * rz;
    o[j] = x > 0.0f ? x : (__builtin_amdgcn_exp2f(x * kLog2e) - 1.0f);
  }
  reinterpret_cast<f32x4*>(out)[(size_t)n * 64 + hh * 16 + d4] = o;
}

extern "C" void kernel_launch(void* const* d_in, const int* in_sizes, int n_in,
                              void* d_out, int out_size, void* d_ws, size_t ws_size,
                              hipStream_t stream) {
  const float* hmat  = (const float*)d_in[0];
  const float* adj   = (const float*)d_in[1];
  const float* W     = (const float*)d_in[2];
  const float* a_src = (const float*)d_in[3];
  const float* a_dst = (const float*)d_in[4];
  float* out = (float*)d_out;

  char* ws = (char*)d_ws;
  unsigned short* whb   = (unsigned short*)(ws);             // 2 MB    @0
  unsigned short* wfrag = (unsigned short*)(ws + 0x200000);  // 128 KB (dead after k_wh)
  float* zP     = (float*)(ws + 0x200000);                   // 128 KB (reuses wfrag)
  float* s_src  = (float*)(ws + 0x220000);                   // 64 KB
  float* s_dst  = (float*)(ws + 0x230000);                   // 64 KB
  unsigned int* MhKey = (unsigned int*)(ws + 0x240000);      // 64 B
  unsigned int* bits = (unsigned int*)(ws + 0x241000);       // 2 MB
  float* accP   = (float*)(ws + 0x441000);                   // 8 MB (2 col-splits)

  hipMemsetAsync(ws + 0x240000, 0, 64, stream);  // MhKey only
  hipLaunchKernelGGL(k_wswz, dim3(4), dim3(256), 0, stream, W, wfrag);
  hipLaunchKernelGGL(k_wh, dim3(256), dim3(256), 0, stream,
                     hmat, wfrag, a_src, a_dst, whb, s_src, s_dst, MhKey);
  hipLaunchKernelGGL(k_abits, dim3(4096), dim3(256), 0, stream, adj, bits);
  hipLaunchKernelGGL(k_attn, dim3(512), dim3(512), 0, stream,
                     (const unsigned char*)bits, whb, s_src, s_dst, MhKey, accP, zP);
  hipLaunchKernelGGL(k_fin, dim3(1024), dim3(256), 0, stream, accP, zP, out);
}

// Round 6
// 75.337 us; speedup vs baseline: 1.2143x; 1.0349x over previous
//
#include <hip/hip_runtime.h>

typedef __attribute__((ext_vector_type(4))) float f32x4;
typedef __attribute__((ext_vector_type(8))) short short8;
typedef __attribute__((ext_vector_type(8))) __bf16 bf16x8;

constexpr int kN = 4096;
constexpr int kF = 256;
constexpr int kH = 4;
constexpr int kD = 64;
constexpr float kLog2e = 1.4426950408889634f;

__device__ __forceinline__ unsigned short f2us(float x) {
  __bf16 b = (__bf16)x;
  return __builtin_bit_cast(unsigned short, b);
}

// ---------------------------------------------------------------------------
// k_wswz: W (fp32, HxFxD) -> bf16 MFMA B-fragments for k_wh.
// Also zeroes MhKey[h] (stream order guarantees this lands before k_wh).
// ---------------------------------------------------------------------------
__global__ __launch_bounds__(256) void k_wswz(const float* __restrict__ W,
                                              unsigned short* __restrict__ wfrag,
                                              unsigned int* __restrict__ MhKey) {
  const int h = blockIdx.x;
  const int t = threadIdx.x;
  if (t == 0) MhKey[h] = 0u;
#pragma unroll
  for (int j = 0; j < 8; j++) {
    const int lf = t + j * 256;  // 0..2047
    const int lane = lf & 63;
    const int dt = (lf >> 6) & 3;
    const int ks = lf >> 8;
    const int d = dt * 16 + (lane & 15);
    const int i0 = ks * 32 + 8 * (lane >> 4);
    unsigned short v[8];
#pragma unroll
    for (int e = 0; e < 8; e++)
      v[e] = f2us(W[((size_t)h * kF + i0 + e) * kD + d]);
    *reinterpret_cast<short8*>(wfrag + ((size_t)(h * 2048 + lf) << 3)) =
        *reinterpret_cast<const short8*>(v);
  }
}

// ---------------------------------------------------------------------------
// k_wh: Wh = h @ W[h] via MFMA; writes whb (bf16, pre-swizzled B-frag order)
// + s_src/s_dst (fp32 acc dotted with a vectors) + atomicMax'ed max-key.
// ---------------------------------------------------------------------------
__global__ __launch_bounds__(256) void k_wh(const float* __restrict__ hmat,
                                            const unsigned short* __restrict__ wfrag,
                                            const float* __restrict__ a_src,
                                            const float* __restrict__ a_dst,
                                            unsigned short* __restrict__ whb,
                                            float* __restrict__ s_src,
                                            float* __restrict__ s_dst,
                                            unsigned int* __restrict__ MhKey) {
  const int h = blockIdx.x & 3, rb = blockIdx.x >> 2;
  const int row0 = rb * 64;
  const int t = threadIdx.x;
  const int wave = t >> 6, lane = t & 63;
  const int lr = lane & 15, lg = lane >> 4;
  const int nrow = row0 + wave * 16 + lr;
  f32x4 acc[4] = {};
  const float* hrow = hmat + (size_t)nrow * kF + 8 * lg;
  const short8* wf = reinterpret_cast<const short8*>(wfrag) + h * 2048 + lane;
#pragma unroll
  for (int ks = 0; ks < 8; ks++) {
    const f32x4 h0 = *reinterpret_cast<const f32x4*>(hrow + ks * 32);
    const f32x4 h1 = *reinterpret_cast<const f32x4*>(hrow + ks * 32 + 4);
    bf16x8 af;
#pragma unroll
    for (int j = 0; j < 4; j++) { af[j] = (__bf16)h0[j]; af[4 + j] = (__bf16)h1[j]; }
#pragma unroll
    for (int dt = 0; dt < 4; dt++) {
      const short8 bs = wf[(ks * 4 + dt) * 64];
      acc[dt] = __builtin_amdgcn_mfma_f32_16x16x32_bf16(af, __builtin_bit_cast(bf16x8, bs), acc[dt], 0, 0, 0);
    }
  }
#pragma unroll
  for (int dt = 0; dt < 4; dt++) {
#pragma unroll
    for (int r = 0; r < 4; r++) {
      const int n = row0 + wave * 16 + lg * 4 + r;
      const int mstep = n >> 5, kl = n & 31;
      const int lane2 = ((kl >> 3) << 4) | lr;
      const int e = kl & 7;
      whb[((((size_t)(h * 128 + mstep) * 4 + dt) * 64 + lane2) << 3) + e] = f2us(acc[dt][r]);
    }
  }
  float as4[4], ad4[4];
#pragma unroll
  for (int dt = 0; dt < 4; dt++) {
    as4[dt] = a_src[h * kD + dt * 16 + lr];
    ad4[dt] = a_dst[h * kD + dt * 16 + lr];
  }
  float wmax = -1e30f;
#pragma unroll
  for (int r = 0; r < 4; r++) {
    float ps = acc[0][r] * as4[0] + acc[1][r] * as4[1] + acc[2][r] * as4[2] + acc[3][r] * as4[3];
    float pd = acc[0][r] * ad4[0] + acc[1][r] * ad4[1] + acc[2][r] * ad4[2] + acc[3][r] * ad4[3];
#pragma unroll
    for (int off = 1; off < 16; off <<= 1) {
      ps += __shfl_xor(ps, off);
      pd += __shfl_xor(pd, off);
    }
    const int n = row0 + wave * 16 + lg * 4 + r;
    if (lr == 0) { s_src[h * kN + n] = ps; s_dst[h * kN + n] = pd; }
    wmax = fmaxf(wmax, pd);
  }
  wmax = fmaxf(wmax, __shfl_xor(wmax, 16));
  wmax = fmaxf(wmax, __shfl_xor(wmax, 32));
  if (lane == 0) {
    const unsigned int key = (unsigned int)fmaxf(0.0f, (wmax + 512.0f) * 4096.0f) + 1u;
    atomicMax(&MhKey[h], key);
  }
}

// ---------------------------------------------------------------------------
// k_abits: adj (fp32 0/1) -> bitmask via __ballot (coalesced 256B loads).
// ---------------------------------------------------------------------------
__global__ __launch_bounds__(256) void k_abits(const float* __restrict__ adj,
                                               unsigned int* __restrict__ bits) {
  const int gw = (blockIdx.x * 256 + threadIdx.x) >> 6;  // wave id, 16384 total
  const int lane = threadIdx.x & 63;
  const size_t ebase = (size_t)gw * 1024;
  const float* p = adj + ebase + lane;
  unsigned int myword = 0;
#pragma unroll
  for (int c = 0; c < 16; c++) {
    const unsigned long long b = __ballot(p[c * 64] != 0.0f);
    const unsigned int sel = (lane & 1) ? (unsigned int)(b >> 32) : (unsigned int)b;
    if ((lane >> 1) == c) myword = sel;
  }
  if (lane < 32) bits[(ebase >> 5) + lane] = myword;
}

// p = mask * max(E1*K1, E2*K2)
__device__ __forceinline__ bf16x8 make_p2(const f32x4 E1a, const f32x4 E1b,
                                          const f32x4 E2a, const f32x4 E2b,
                                          const float K1, const float K2,
                                          const unsigned int m) {
  bf16x8 r;
#pragma unroll
  for (int j = 0; j < 4; j++) {
    const float pv = fmaxf(E1a[j] * K1, E2a[j] * K2);
    r[j] = (__bf16)((m & (1u << j)) ? pv : 0.0f);
  }
#pragma unroll
  for (int j = 0; j < 4; j++) {
    const float pv = fmaxf(E1b[j] * K1, E2b[j] * K2);
    r[4 + j] = (__bf16)((m & (16u << j)) ? pv : 0.0f);
  }
  return r;
}

// ---------------------------------------------------------------------------
// k_attn: 512 blocks = 256 rowgroups(16 rows) x 2 col-halves(2048).
// 8 waves = 4 heads x 2 col-interleaves (q). q partials combined via LDS;
// each (cs,h,n,d) partial written exactly once; k_fin combines col-splits.
// ---------------------------------------------------------------------------
__global__ __launch_bounds__(512, 4) void k_attn(const unsigned char* __restrict__ bitsb,
                                                 const unsigned short* __restrict__ whb,
                                                 const float* __restrict__ s_src,
                                                 const float* __restrict__ s_dst,
                                                 const unsigned int* __restrict__ MhKey,
                                                 float* __restrict__ accP,
                                                 float* __restrict__ zP) {
  const int bid = blockIdx.x;
  const int rb = bid >> 1, cs = bid & 1;
  const int row0 = rb * 16;
  const int colbase = cs * 2048;
  const int t = threadIdx.x;
  const int wave = t >> 6, lane = t & 63;
  const int h = wave & 3, q = wave >> 2;
  const int lr = lane & 15, lg = lane >> 4;

  __shared__ float el1[4][2048];
  __shared__ float el2[4][2048];
  __shared__ float zx[4][16];

#pragma unroll
  for (int j = 0; j < 4; j++) {
    const int idx = t + j * 512;  // 0..2047 f32x4 slots
    const int hh = idx >> 9, c4 = (idx & 511) * 4;
    const f32x4 sd = *reinterpret_cast<const f32x4*>(s_dst + hh * kN + colbase + c4);
    f32x4 e1, e2;
#pragma unroll
    for (int i = 0; i < 4; i++) {
      const float u = sd[i] * kLog2e;
      e1[i] = __builtin_amdgcn_exp2f(u);
      e2[i] = __builtin_amdgcn_exp2f(0.2f * u);
    }
    *reinterpret_cast<f32x4*>(&el1[hh][c4]) = e1;
    *reinterpret_cast<f32x4*>(&el2[hh][c4]) = e2;
  }
  __syncthreads();

  const float M = (float)MhKey[h] * (1.0f / 4096.0f) - 512.0f;
  const float A = s_src[h * kN + row0 + lr];
  const float xb = A + M;
  const float B = fmaxf(xb, 0.2f * xb);
  const float K1 = __builtin_amdgcn_exp2f((A - B) * kLog2e);
  const float K2 = __builtin_amdgcn_exp2f((0.2f * A - B) * kLog2e);

  f32x4 acc[4] = {};
  f32x4 accz = {};
  bf16x8 ones;
#pragma unroll
  for (int e = 0; e < 8; e++) ones[e] = (__bf16)1.0f;

  const size_t mB = (size_t)(row0 + lr) * 512 + (colbase >> 3) + q * 4 + lg;
  const float* e1p = &el1[h][q * 32 + 8 * lg];
  const float* e2p = &el2[h][q * 32 + 8 * lg];
  const short8* wb = reinterpret_cast<const short8*>(whb) + (size_t)h * 32768 + lane;
  const int mstep0 = cs * 64 + q;

  unsigned int ma = bitsb[mB];
  unsigned int mb = bitsb[mB + 8];
  short8 bw0, bw1, bw2, bw3;
  {
    const short8* p = wb + (size_t)mstep0 * 256;
    bw0 = p[0]; bw1 = p[64]; bw2 = p[128]; bw3 = p[192];
  }

  for (int it = 0; it < 32; it++) {
    const unsigned int cm = ma;
    ma = mb;
    if (it + 2 < 32) mb = bitsb[mB + (it + 2) * 8];

    const short8 cb0 = bw0, cb1 = bw1, cb2 = bw2, cb3 = bw3;
    if (it + 1 < 32) {
      const short8* p = wb + (size_t)(mstep0 + (it + 1) * 2) * 256;
      bw0 = p[0]; bw1 = p[64]; bw2 = p[128]; bw3 = p[192];
    }

    const f32x4 E1a = *reinterpret_cast<const f32x4*>(e1p + it * 64);
    const f32x4 E1b = *reinterpret_cast<const f32x4*>(e1p + it * 64 + 4);
    const f32x4 E2a = *reinterpret_cast<const f32x4*>(e2p + it * 64);
    const f32x4 E2b = *reinterpret_cast<const f32x4*>(e2p + it * 64 + 4);

    const bf16x8 P0 = make_p2(E1a, E1b, E2a, E2b, K1, K2, cm);
    const bf16x8 B0 = __builtin_bit_cast(bf16x8, cb0);
    const bf16x8 B1 = __builtin_bit_cast(bf16x8, cb1);
    const bf16x8 B2 = __builtin_bit_cast(bf16x8, cb2);
    const bf16x8 B3 = __builtin_bit_cast(bf16x8, cb3);

    acc[0] = __builtin_amdgcn_mfma_f32_16x16x32_bf16(P0, B0, acc[0], 0, 0, 0);
    acc[1] = __builtin_amdgcn_mfma_f32_16x16x32_bf16(P0, B1, acc[1], 0, 0, 0);
    acc[2] = __builtin_amdgcn_mfma_f32_16x16x32_bf16(P0, B2, acc[2], 0, 0, 0);
    acc[3] = __builtin_amdgcn_mfma_f32_16x16x32_bf16(P0, B3, acc[3], 0, 0, 0);
    accz   = __builtin_amdgcn_mfma_f32_16x16x32_bf16(P0, ones, accz, 0, 0, 0);
  }

  // ---- q-combine via LDS (el1 is dead now), then single plain store ----
  __syncthreads();
  if (q == 1) {
    float* dst = &el1[h][0];
#pragma unroll
    for (int dt = 0; dt < 4; dt++)
      *reinterpret_cast<f32x4*>(dst + (dt * 64 + lane) * 4) = acc[dt];
    if (lr == 0) {
#pragma unroll
      for (int r = 0; r < 4; r++) zx[h][lg * 4 + r] = accz[r];
    }
  }
  __syncthreads();
  if (q == 0) {
    const float* src = &el1[h][0];
#pragma unroll
    for (int dt = 0; dt < 4; dt++)
      acc[dt] += *reinterpret_cast<const f32x4*>(src + (dt * 64 + lane) * 4);

    const size_t ob = ((size_t)(cs * 4 + h) * kN + row0) * kD;
#pragma unroll
    for (int dt = 0; dt < 4; dt++)
#pragma unroll
      for (int r = 0; r < 4; r++)
        accP[ob + (size_t)(lg * 4 + r) * kD + dt * 16 + lr] = acc[dt][r];
    if (lr == 0) {
#pragma unroll
      for (int r = 0; r < 4; r++)
        zP[(size_t)(cs * 4 + h) * kN + row0 + lg * 4 + r] = accz[r] + zx[h][lg * 4 + r];
    }
  }
}

// ---------------------------------------------------------------------------
// k_fin: out[n][h*64+d] = elu( (acc0+acc1) / (z0+z1) )
// ---------------------------------------------------------------------------
__global__ __launch_bounds__(256) void k_fin(const float* __restrict__ accP,
                                             const float* __restrict__ zP,
                                             float* __restrict__ out) {
  const int idx = blockIdx.x * 256 + threadIdx.x;  // 262144 float4s
  const int d4 = idx & 15;
  const int hh = (idx >> 4) & 3;
  const int n = idx >> 6;
  const f32x4 v0 = reinterpret_cast<const f32x4*>(accP)[((size_t)hh * kN + n) * 16 + d4];
  const f32x4 v1 = reinterpret_cast<const f32x4*>(accP)[((size_t)(4 + hh) * kN + n) * 16 + d4];
  const f32x4 v = v0 + v1;
  const float z = zP[(size_t)hh * kN + n] + zP[(size_t)(4 + hh) * kN + n];
  const float rz = 1.0f / z;
  f32x4 o;
#pragma unroll
  for (int j = 0; j < 4; j++) {
    const float x = v[j] * rz;
    o[j] = x > 0.0f ? x : (__builtin_amdgcn_exp2f(x * kLog2e) - 1.0f);
  }
  reinterpret_cast<f32x4*>(out)[(size_t)n * 64 + hh * 16 + d4] = o;
}

extern "C" void kernel_launch(void* const* d_in, const int* in_sizes, int n_in,
                              void* d_out, int out_size, void* d_ws, size_t ws_size,
                              hipStream_t stream) {
  const float* hmat  = (const float*)d_in[0];
  const float* adj   = (const float*)d_in[1];
  const float* W     = (const float*)d_in[2];
  const float* a_src = (const float*)d_in[3];
  const float* a_dst = (const float*)d_in[4];
  float* out = (float*)d_out;

  char* ws = (char*)d_ws;
  unsigned short* whb   = (unsigned short*)(ws);             // 2 MB    @0
  unsigned short* wfrag = (unsigned short*)(ws + 0x200000);  // 128 KB (dead after k_wh)
  float* zP     = (float*)(ws + 0x200000);                   // 128 KB (reuses wfrag)
  float* s_src  = (float*)(ws + 0x220000);                   // 64 KB
  float* s_dst  = (float*)(ws + 0x230000);                   // 64 KB
  unsigned int* MhKey = (unsigned int*)(ws + 0x240000);      // 64 B
  unsigned int* bits = (unsigned int*)(ws + 0x241000);       // 2 MB
  float* accP   = (float*)(ws + 0x441000);                   // 8 MB (2 col-splits)

  hipLaunchKernelGGL(k_wswz, dim3(4), dim3(256), 0, stream, W, wfrag, MhKey);
  hipLaunchKernelGGL(k_wh, dim3(256), dim3(256), 0, stream,
                     hmat, wfrag, a_src, a_dst, whb, s_src, s_dst, MhKey);
  hipLaunchKernelGGL(k_abits, dim3(4096), dim3(256), 0, stream, adj, bits);
  hipLaunchKernelGGL(k_attn, dim3(512), dim3(512), 0, stream,
                     (const unsigned char*)bits, whb, s_src, s_dst, MhKey, accP, zP);
  hipLaunchKernelGGL(k_fin, dim3(1024), dim3(256), 0, stream, accP, zP, out);
}

// Round 7
// 65.971 us; speedup vs baseline: 1.3867x; 1.1420x over previous
//
#include <hip/hip_runtime.h>

typedef __attribute__((ext_vector_type(4))) float f32x4;
typedef __attribute__((ext_vector_type(4))) unsigned int u32x4;
typedef __attribute__((ext_vector_type(8))) short short8;
typedef __attribute__((ext_vector_type(8))) __bf16 bf16x8;

constexpr int kN = 4096;
constexpr int kF = 256;
constexpr int kH = 4;
constexpr int kD = 64;
constexpr float kLog2e = 1.4426950408889634f;

__device__ __forceinline__ unsigned short f2us(float x) {
  __bf16 b = (__bf16)x;
  return __builtin_bit_cast(unsigned short, b);
}

// ---------------------------------------------------------------------------
// k_wswz: W (fp32, HxFxD) -> bf16 MFMA B-fragments for k_wh. Zeroes MhKey.
// ---------------------------------------------------------------------------
__global__ __launch_bounds__(256) void k_wswz(const float* __restrict__ W,
                                              unsigned short* __restrict__ wfrag,
                                              unsigned int* __restrict__ MhKey) {
  const int h = blockIdx.x;
  const int t = threadIdx.x;
  if (t == 0) MhKey[h] = 0u;
#pragma unroll
  for (int j = 0; j < 8; j++) {
    const int lf = t + j * 256;  // 0..2047
    const int lane = lf & 63;
    const int dt = (lf >> 6) & 3;
    const int ks = lf >> 8;
    const int d = dt * 16 + (lane & 15);
    const int i0 = ks * 32 + 8 * (lane >> 4);
    unsigned short v[8];
#pragma unroll
    for (int e = 0; e < 8; e++)
      v[e] = f2us(W[((size_t)h * kF + i0 + e) * kD + d]);
    *reinterpret_cast<short8*>(wfrag + ((size_t)(h * 2048 + lf) << 3)) =
        *reinterpret_cast<const short8*>(v);
  }
}

// ---------------------------------------------------------------------------
// k_wh: Wh = h @ W[h] via MFMA; writes whb (bf16, pre-swizzled B-frag order)
// + s_src/s_dst + atomicMax'ed max-key.
// ---------------------------------------------------------------------------
__global__ __launch_bounds__(256) void k_wh(const float* __restrict__ hmat,
                                            const unsigned short* __restrict__ wfrag,
                                            const float* __restrict__ a_src,
                                            const float* __restrict__ a_dst,
                                            unsigned short* __restrict__ whb,
                                            float* __restrict__ s_src,
                                            float* __restrict__ s_dst,
                                            unsigned int* __restrict__ MhKey) {
  const int h = blockIdx.x & 3, rb = blockIdx.x >> 2;
  const int row0 = rb * 64;
  const int t = threadIdx.x;
  const int wave = t >> 6, lane = t & 63;
  const int lr = lane & 15, lg = lane >> 4;
  const int nrow = row0 + wave * 16 + lr;
  f32x4 acc[4] = {};
  const float* hrow = hmat + (size_t)nrow * kF + 8 * lg;
  const short8* wf = reinterpret_cast<const short8*>(wfrag) + h * 2048 + lane;
#pragma unroll
  for (int ks = 0; ks < 8; ks++) {
    const f32x4 h0 = *reinterpret_cast<const f32x4*>(hrow + ks * 32);
    const f32x4 h1 = *reinterpret_cast<const f32x4*>(hrow + ks * 32 + 4);
    bf16x8 af;
#pragma unroll
    for (int j = 0; j < 4; j++) { af[j] = (__bf16)h0[j]; af[4 + j] = (__bf16)h1[j]; }
#pragma unroll
    for (int dt = 0; dt < 4; dt++) {
      const short8 bs = wf[(ks * 4 + dt) * 64];
      acc[dt] = __builtin_amdgcn_mfma_f32_16x16x32_bf16(af, __builtin_bit_cast(bf16x8, bs), acc[dt], 0, 0, 0);
    }
  }
#pragma unroll
  for (int dt = 0; dt < 4; dt++) {
#pragma unroll
    for (int r = 0; r < 4; r++) {
      const int n = row0 + wave * 16 + lg * 4 + r;
      const int mstep = n >> 5, kl = n & 31;
      const int lane2 = ((kl >> 3) << 4) | lr;
      const int e = kl & 7;
      whb[((((size_t)(h * 128 + mstep) * 4 + dt) * 64 + lane2) << 3) + e] = f2us(acc[dt][r]);
    }
  }
  float as4[4], ad4[4];
#pragma unroll
  for (int dt = 0; dt < 4; dt++) {
    as4[dt] = a_src[h * kD + dt * 16 + lr];
    ad4[dt] = a_dst[h * kD + dt * 16 + lr];
  }
  float wmax = -1e30f;
#pragma unroll
  for (int r = 0; r < 4; r++) {
    float ps = acc[0][r] * as4[0] + acc[1][r] * as4[1] + acc[2][r] * as4[2] + acc[3][r] * as4[3];
    float pd = acc[0][r] * ad4[0] + acc[1][r] * ad4[1] + acc[2][r] * ad4[2] + acc[3][r] * ad4[3];
#pragma unroll
    for (int off = 1; off < 16; off <<= 1) {
      ps += __shfl_xor(ps, off);
      pd += __shfl_xor(pd, off);
    }
    const int n = row0 + wave * 16 + lg * 4 + r;
    if (lr == 0) { s_src[h * kN + n] = ps; s_dst[h * kN + n] = pd; }
    wmax = fmaxf(wmax, pd);
  }
  wmax = fmaxf(wmax, __shfl_xor(wmax, 16));
  wmax = fmaxf(wmax, __shfl_xor(wmax, 32));
  if (lane == 0) {
    const unsigned int key = (unsigned int)fmaxf(0.0f, (wmax + 512.0f) * 4096.0f) + 1u;
    atomicMax(&MhKey[h], key);
  }
}

// ---------------------------------------------------------------------------
// k_abits: adj (fp32 0/1) -> TRANSPOSED bitmask bitsT.
// Per row r (512 bytes): chunkId = cs*8 + q*4 + lg (16 chunks of 32 bytes);
// byte `it` of chunk covers cols cs*2048 + it*64 + q*32 + lg*8 + [0..8).
// So each k_attn lane's 32 iteration-bytes are CONTIGUOUS -> 2 dwordx4 loads.
// ---------------------------------------------------------------------------
__global__ __launch_bounds__(256) void k_abits(const float* __restrict__ adj,
                                               unsigned char* __restrict__ bitsT) {
  const int gw = (blockIdx.x * 256 + threadIdx.x) >> 6;  // wave id, 16384 total
  const int lane = threadIdx.x & 63;
  const int r = gw >> 2, cb = gw & 3;
  const size_t ebase = (size_t)gw * 1024;
  const float* p = adj + ebase + lane;
  unsigned int myword = 0;
#pragma unroll
  for (int c = 0; c < 16; c++) {
    const unsigned long long b = __ballot(p[c * 64] != 0.0f);
    const unsigned int sel = (lane & 1) ? (unsigned int)(b >> 32) : (unsigned int)b;
    if ((lane >> 1) == c) myword = sel;
  }
  if (lane < 32) {
    const int w = cb * 32 + lane;  // word index within row, covers cols [w*32, +32)
    const int cs = w >> 6, rem = w & 63;
    const int q = rem & 1, it = rem >> 1;
    const size_t base = (size_t)r * 512 + (size_t)it;
#pragma unroll
    for (int k = 0; k < 4; k++)
      bitsT[base + (size_t)((cs << 3) + (q << 2) + k) * 32] =
          (unsigned char)((myword >> (8 * k)) & 0xFFu);
  }
}

// p = mask * max(E1*K1, E2*K2)
__device__ __forceinline__ bf16x8 make_p2(const f32x4 E1a, const f32x4 E1b,
                                          const f32x4 E2a, const f32x4 E2b,
                                          const float K1, const float K2,
                                          const unsigned int m) {
  bf16x8 r;
#pragma unroll
  for (int j = 0; j < 4; j++) {
    const float pv = fmaxf(E1a[j] * K1, E2a[j] * K2);
    r[j] = (__bf16)((m & (1u << j)) ? pv : 0.0f);
  }
#pragma unroll
  for (int j = 0; j < 4; j++) {
    const float pv = fmaxf(E1b[j] * K1, E2b[j] * K2);
    r[4 + j] = (__bf16)((m & (16u << j)) ? pv : 0.0f);
  }
  return r;
}

// ---------------------------------------------------------------------------
// k_attn: 512 blocks = 256 rowgroups(16) x 2 col-halves(2048). 8 waves =
// 4 heads x 2 col-interleaves (q). Mask bits live in registers for the whole
// loop (2 dwordx4 from the transposed bitmask). B-frags 2-deep prefetched,
// fully unrolled (all reg indices literal). q partials combined via LDS.
// ---------------------------------------------------------------------------
__global__ __launch_bounds__(512, 4) void k_attn(const unsigned char* __restrict__ bitsT,
                                                 const unsigned short* __restrict__ whb,
                                                 const float* __restrict__ s_src,
                                                 const float* __restrict__ s_dst,
                                                 const unsigned int* __restrict__ MhKey,
                                                 float* __restrict__ accP,
                                                 float* __restrict__ zP) {
  const int bid = blockIdx.x;
  const int rb = bid >> 1, cs = bid & 1;
  const int row0 = rb * 16;
  const int colbase = cs * 2048;
  const int t = threadIdx.x;
  const int wave = t >> 6, lane = t & 63;
  const int h = wave & 3, q = wave >> 2;
  const int lr = lane & 15, lg = lane >> 4;

  __shared__ float el1[4][2048];
  __shared__ float el2[4][2048];
  __shared__ float zx[4][16];

#pragma unroll
  for (int j = 0; j < 4; j++) {
    const int idx = t + j * 512;  // 0..2047 f32x4 slots
    const int hh = idx >> 9, c4 = (idx & 511) * 4;
    const f32x4 sd = *reinterpret_cast<const f32x4*>(s_dst + hh * kN + colbase + c4);
    f32x4 e1, e2;
#pragma unroll
    for (int i = 0; i < 4; i++) {
      const float u = sd[i] * kLog2e;
      e1[i] = __builtin_amdgcn_exp2f(u);
      e2[i] = __builtin_amdgcn_exp2f(0.2f * u);
    }
    *reinterpret_cast<f32x4*>(&el1[hh][c4]) = e1;
    *reinterpret_cast<f32x4*>(&el2[hh][c4]) = e2;
  }
  __syncthreads();

  const float M = (float)MhKey[h] * (1.0f / 4096.0f) - 512.0f;
  const float A = s_src[h * kN + row0 + lr];
  const float xb = A + M;
  const float B = fmaxf(xb, 0.2f * xb);
  const float K1 = __builtin_amdgcn_exp2f((A - B) * kLog2e);
  const float K2 = __builtin_amdgcn_exp2f((0.2f * A - B) * kLog2e);

  f32x4 acc[4] = {};
  f32x4 accz = {};
  bf16x8 ones;
#pragma unroll
  for (int e = 0; e < 8; e++) ones[e] = (__bf16)1.0f;

  // mask: all 32 iteration-bytes contiguous per lane in bitsT
  const size_t mBase = (size_t)(row0 + lr) * 512 + (size_t)((cs << 3) + (q << 2) + lg) * 32;
  const u32x4 m0 = *reinterpret_cast<const u32x4*>(bitsT + mBase);       // it 0..15
  const u32x4 m1 = *reinterpret_cast<const u32x4*>(bitsT + mBase + 16);  // it 16..31

  const float* e1p = &el1[h][q * 32 + 8 * lg];
  const float* e2p = &el2[h][q * 32 + 8 * lg];
  const short8* wb = reinterpret_cast<const short8*>(whb) + (size_t)h * 32768 + lane;
  const int mstep0 = cs * 64 + q;

  // 2-deep B-frag prefetch (unguarded overflow prefetches read in-ws garbage,
  // never consumed)
  short8 bw[2][4];
#pragma unroll
  for (int s = 0; s < 2; s++) {
    const short8* p = wb + (size_t)(mstep0 + s * 2) * 256;
    bw[s][0] = p[0]; bw[s][1] = p[64]; bw[s][2] = p[128]; bw[s][3] = p[192];
  }

#define UNIT(ITC, CM)                                                          \
  {                                                                            \
    const short8 cb0 = bw[(ITC) & 1][0], cb1 = bw[(ITC) & 1][1],               \
                 cb2 = bw[(ITC) & 1][2], cb3 = bw[(ITC) & 1][3];               \
    const short8* pp = wb + (size_t)(mstep0 + ((ITC) + 2) * 2) * 256;          \
    bw[(ITC) & 1][0] = pp[0];                                                  \
    bw[(ITC) & 1][1] = pp[64];                                                 \
    bw[(ITC) & 1][2] = pp[128];                                                \
    bw[(ITC) & 1][3] = pp[192];                                                \
    const f32x4 E1a = *reinterpret_cast<const f32x4*>(e1p + (ITC) * 64);       \
    const f32x4 E1b = *reinterpret_cast<const f32x4*>(e1p + (ITC) * 64 + 4);   \
    const f32x4 E2a = *reinterpret_cast<const f32x4*>(e2p + (ITC) * 64);       \
    const f32x4 E2b = *reinterpret_cast<const f32x4*>(e2p + (ITC) * 64 + 4);   \
    const bf16x8 P0 = make_p2(E1a, E1b, E2a, E2b, K1, K2, (CM));               \
    acc[0] = __builtin_amdgcn_mfma_f32_16x16x32_bf16(                          \
        P0, __builtin_bit_cast(bf16x8, cb0), acc[0], 0, 0, 0);                 \
    acc[1] = __builtin_amdgcn_mfma_f32_16x16x32_bf16(                          \
        P0, __builtin_bit_cast(bf16x8, cb1), acc[1], 0, 0, 0);                 \
    acc[2] = __builtin_amdgcn_mfma_f32_16x16x32_bf16(                          \
        P0, __builtin_bit_cast(bf16x8, cb2), acc[2], 0, 0, 0);                 \
    acc[3] = __builtin_amdgcn_mfma_f32_16x16x32_bf16(                          \
        P0, __builtin_bit_cast(bf16x8, cb3), acc[3], 0, 0, 0);                 \
    accz = __builtin_amdgcn_mfma_f32_16x16x32_bf16(P0, ones, accz, 0, 0, 0);   \
  }

#pragma unroll
  for (int it = 0; it < 16; ++it) {
    const unsigned cm = (m0[it >> 2] >> ((it & 3) * 8)) & 0xFFu;
    UNIT(it, cm);
  }
#pragma unroll
  for (int it2 = 0; it2 < 16; ++it2) {
    const int it = it2 + 16;
    const unsigned cm = (m1[it2 >> 2] >> ((it2 & 3) * 8)) & 0xFFu;
    UNIT(it, cm);
  }
#undef UNIT

  // ---- q-combine via LDS (el1 is dead now), then single plain store ----
  __syncthreads();
  if (q == 1) {
    float* dst = &el1[h][0];
#pragma unroll
    for (int dt = 0; dt < 4; dt++)
      *reinterpret_cast<f32x4*>(dst + (dt * 64 + lane) * 4) = acc[dt];
    if (lr == 0) {
#pragma unroll
      for (int r = 0; r < 4; r++) zx[h][lg * 4 + r] = accz[r];
    }
  }
  __syncthreads();
  if (q == 0) {
    const float* src = &el1[h][0];
#pragma unroll
    for (int dt = 0; dt < 4; dt++)
      acc[dt] += *reinterpret_cast<const f32x4*>(src + (dt * 64 + lane) * 4);

    const size_t ob = ((size_t)(cs * 4 + h) * kN + row0) * kD;
#pragma unroll
    for (int dt = 0; dt < 4; dt++)
#pragma unroll
      for (int r = 0; r < 4; r++)
        accP[ob + (size_t)(lg * 4 + r) * kD + dt * 16 + lr] = acc[dt][r];
    if (lr == 0) {
#pragma unroll
      for (int r = 0; r < 4; r++)
        zP[(size_t)(cs * 4 + h) * kN + row0 + lg * 4 + r] = accz[r] + zx[h][lg * 4 + r];
    }
  }
}

// ---------------------------------------------------------------------------
// k_fin: out[n][h*64+d] = elu( (acc0+acc1) / (z0+z1) )
// ---------------------------------------------------------------------------
__global__ __launch_bounds__(256) void k_fin(const float* __restrict__ accP,
                                             const float* __restrict__ zP,
                                             float* __restrict__ out) {
  const int idx = blockIdx.x * 256 + threadIdx.x;  // 262144 float4s
  const int d4 = idx & 15;
  const int hh = (idx >> 4) & 3;
  const int n = idx >> 6;
  const f32x4 v0 = reinterpret_cast<const f32x4*>(accP)[((size_t)hh * kN + n) * 16 + d4];
  const f32x4 v1 = reinterpret_cast<const f32x4*>(accP)[((size_t)(4 + hh) * kN + n) * 16 + d4];
  const f32x4 v = v0 + v1;
  const float z = zP[(size_t)hh * kN + n] + zP[(size_t)(4 + hh) * kN + n];
  const float rz = 1.0f / z;
  f32x4 o;
#pragma unroll
  for (int j = 0; j < 4; j++) {
    const float x = v[j] * rz;
    o[j] = x > 0.0f ? x : (__builtin_amdgcn_exp2f(x * kLog2e) - 1.0f);
  }
  reinterpret_cast<f32x4*>(out)[(size_t)n * 64 + hh * 16 + d4] = o;
}

extern "C" void kernel_launch(void* const* d_in, const int* in_sizes, int n_in,
                              void* d_out, int out_size, void* d_ws, size_t ws_size,
                              hipStream_t stream) {
  const float* hmat  = (const float*)d_in[0];
  const float* adj   = (const float*)d_in[1];
  const float* W     = (const float*)d_in[2];
  const float* a_src = (const float*)d_in[3];
  const float* a_dst = (const float*)d_in[4];
  float* out = (float*)d_out;

  char* ws = (char*)d_ws;
  unsigned short* whb   = (unsigned short*)(ws);             // 2 MB    @0
  unsigned short* wfrag = (unsigned short*)(ws + 0x200000);  // 128 KB (dead after k_wh)
  float* zP     = (float*)(ws + 0x200000);                   // 128 KB (reuses wfrag)
  float* s_src  = (float*)(ws + 0x220000);                   // 64 KB
  float* s_dst  = (float*)(ws + 0x230000);                   // 64 KB
  unsigned int* MhKey = (unsigned int*)(ws + 0x240000);      // 64 B
  unsigned char* bitsT = (unsigned char*)(ws + 0x241000);    // 2 MB (transposed)
  float* accP   = (float*)(ws + 0x441000);                   // 8 MB (2 col-splits)

  hipLaunchKernelGGL(k_wswz, dim3(4), dim3(256), 0, stream, W, wfrag, MhKey);
  hipLaunchKernelGGL(k_wh, dim3(256), dim3(256), 0, stream,
                     hmat, wfrag, a_src, a_dst, whb, s_src, s_dst, MhKey);
  hipLaunchKernelGGL(k_abits, dim3(4096), dim3(256), 0, stream, adj, bitsT);
  hipLaunchKernelGGL(k_attn, dim3(512), dim3(512), 0, stream,
                     bitsT, whb, s_src, s_dst, MhKey, accP, zP);
  hipLaunchKernelGGL(k_fin, dim3(1024), dim3(256), 0, stream, accP, zP, out);
}